// Round 13
// baseline (147.605 us; speedup 1.0000x reference)
//
#include <hip/hip_runtime.h>
#include <cstdint>

#define BDIM 4
#define SEQ 2048
#define DMODEL 1024
#define NH 16
#define HDIM 64

typedef __attribute__((ext_vector_type(8))) short bf16x8;
typedef __attribute__((ext_vector_type(4))) float f32x4;
typedef __attribute__((ext_vector_type(4))) int i32x4;
typedef __attribute__((ext_vector_type(4))) unsigned short u16x4;

#define MFMA16(a, b, c) __builtin_amdgcn_mfma_f32_16x16x32_bf16(a, b, c, 0, 0, 0)

__device__ __forceinline__ unsigned short f2bf(float x) {
    unsigned int u = __float_as_uint(x);
    unsigned int r = (u + 0x7FFFu + ((u >> 16) & 1u)) >> 16;
    return (unsigned short)r;
}

__device__ __forceinline__ void gload16(const void* g, void* l) {
    __builtin_amdgcn_global_load_lds(
        (const __attribute__((address_space(1))) unsigned int*)g,
        (__attribute__((address_space(3))) unsigned int*)l, 16, 0, 0);
}

// ---------------- fused convert fp32 -> bf16 (X and Wq/Wk/Wv in one launch) ----------------
__global__ __launch_bounds__(256) void k_cvt(const float* __restrict__ hs,
                                             const float* __restrict__ wq,
                                             const float* __restrict__ wk,
                                             const float* __restrict__ wv,
                                             unsigned short* __restrict__ Xbf,
                                             unsigned short* __restrict__ Wbf) {
    int i = blockIdx.x * 256 + threadIdx.x;  // float4 index; 11264 blocks total
    if (i < 2097152) {                       // X: 8192 blocks exactly (block-uniform)
        float4 v = ((const float4*)hs)[i];
        u16x4 o = {f2bf(v.x), f2bf(v.y), f2bf(v.z), f2bf(v.w)};
        ((u16x4*)Xbf)[i] = o;
    } else {                                 // W: 3072 blocks
        int j = i - 2097152;                 // 0..786431
        int e = j << 2;
        int which = e >> 20;
        int off = e & 0xFFFFF;
        const float* s = which == 0 ? wq : (which == 1 ? wk : wv);
        float4 v = *(const float4*)(s + off);
        u16x4 o = {f2bf(v.x), f2bf(v.y), f2bf(v.z), f2bf(v.w)};
        ((u16x4*)Wbf)[j] = o;
    }
}

// ---------------- fused QKV GEMM, 256x128 8-phase counted-vmcnt, zero-tail ----------------
// r12's verified schedule (conflicts=0 via slot^=(row>>1)&3 both-sides swizzle)
// at BN=128: grid 768 = EXACTLY 3 rounds of 256 CUs (r12's 384@1/CU = 1.5
// rounds = 75% ceiling, measured occ 16%). Waves 4Mx2N, acc[4][4].
// Counted fences re-derived: STAGE_A=2 loads, STAGE_B=1; vmcnt(6)/3/0.
__global__ __launch_bounds__(512, 2)
void k_qkv(const unsigned short* __restrict__ X,
           const unsigned short* __restrict__ W,
           const float* __restrict__ bq,
           const float* __restrict__ bk,
           const float* __restrict__ bv,
           unsigned short* __restrict__ Qo,
           unsigned short* __restrict__ Ko,
           unsigned short* __restrict__ Vo) {
    __shared__ unsigned short ldsA[2][2][256 * 32];  // 64 KiB
    __shared__ unsigned short ldsB[2][2][128 * 32];  // 32 KiB
    const int tid = threadIdx.x;
    const int lane = tid & 63, wid = tid >> 6;
    const int wm = wid >> 1, wn = wid & 1;   // 4M x 2N
    const int l15 = lane & 15, g = lane >> 4;
    const int bid0 = blockIdx.x;
    const int bid = (bid0 & 7) * 96 + (bid0 >> 3);  // XCD swizzle (768 % 8 == 0)
    const int bx = bid % 24, by = bid / 24;
    const int m0 = by * 256, n0 = bx * 128;

#define STAGE_A(c, kk, kt)                                                         \
    {                                                                              \
        _Pragma("unroll") for (int i = 0; i < 2; ++i) {                            \
            const int e = i * 512 + tid;                                           \
            const int row = e >> 2, cc = e & 3;                                    \
            const int ccx = cc ^ ((row >> 1) & 3);                                 \
            gload16(X + (size_t)(m0 + row) * DMODEL + (kt)*64 + (kk)*32 + ccx * 8, \
                    (char*)&ldsA[c][kk][0] + e * 16);                              \
        }                                                                          \
    }
#define STAGE_B(c, kk, kt)                                                         \
    {                                                                              \
        const int e = tid;                                                         \
        const int row = e >> 2, cc = e & 3;                                        \
        const int ccx = cc ^ ((row >> 1) & 3);                                     \
        gload16(W + (size_t)(n0 + row) * DMODEL + (kt)*64 + (kk)*32 + ccx * 8,     \
                (char*)&ldsB[c][kk][0] + e * 16);                                  \
    }
#define FRAG(base, row) \
    (*(const bf16x8*)((const char*)(base) + (((row)*64 + g * 16) ^ ((((row) >> 1) & 3) << 4))))

    f32x4 acc[4][4];
#pragma unroll
    for (int i = 0; i < 4; ++i)
#pragma unroll
        for (int j = 0; j < 4; ++j) acc[i][j] = (f32x4){0.f, 0.f, 0.f, 0.f};

    // prologue: tile0 kk0+kk1, tile1 kk0   (9 loads/thread; first 3 = tile0 kk0)
    STAGE_A(0, 0, 0); STAGE_B(0, 0, 0);
    STAGE_A(0, 1, 0); STAGE_B(0, 1, 0);
    STAGE_A(1, 0, 1); STAGE_B(1, 0, 1);
    asm volatile("s_waitcnt vmcnt(6)" ::: "memory");
    __builtin_amdgcn_s_barrier();

    const int arow = wm * 64 + l15;    // + mf*16
    const int brow = wn * 64 + l15;    // + nf*16

    for (int t = 0; t < 16; ++t) {
        const int c = t & 1;
        const char* Ab0 = (const char*)&ldsA[c][0][0];
        const char* Ab1 = (const char*)&ldsA[c][1][0];
        const char* Bb0 = (const char*)&ldsB[c][0][0];
        const char* Bb1 = (const char*)&ldsB[c][1][0];

        // ---------- phase 1: kk=0, nfrags {0,1} ----------
        {
            bf16x8 av[4], bv0, bv1;
#pragma unroll
            for (int mf = 0; mf < 4; ++mf) av[mf] = FRAG(Ab0, arow + mf * 16);
            bv0 = FRAG(Bb0, brow);
            bv1 = FRAG(Bb0, brow + 16);
            if (t < 15) STAGE_A(c ^ 1, 1, t + 1);
            __builtin_amdgcn_s_barrier();
            asm volatile("s_waitcnt lgkmcnt(0)" ::: "memory");
            __builtin_amdgcn_sched_barrier(0);
            __builtin_amdgcn_s_setprio(1);
#pragma unroll
            for (int mf = 0; mf < 4; ++mf) {
                acc[mf][0] = MFMA16(av[mf], bv0, acc[mf][0]);
                acc[mf][1] = MFMA16(av[mf], bv1, acc[mf][1]);
            }
            __builtin_amdgcn_s_setprio(0);
            __builtin_amdgcn_s_barrier();

            // ---------- phase 2: kk=0, nfrags {2,3} (av reused) ----------
            bv0 = FRAG(Bb0, brow + 32);
            bv1 = FRAG(Bb0, brow + 48);
            if (t < 15) STAGE_B(c ^ 1, 1, t + 1);
            __builtin_amdgcn_s_barrier();
            asm volatile("s_waitcnt lgkmcnt(0)" ::: "memory");
            __builtin_amdgcn_sched_barrier(0);
            __builtin_amdgcn_s_setprio(1);
#pragma unroll
            for (int mf = 0; mf < 4; ++mf) {
                acc[mf][2] = MFMA16(av[mf], bv0, acc[mf][2]);
                acc[mf][3] = MFMA16(av[mf], bv1, acc[mf][3]);
            }
            __builtin_amdgcn_s_setprio(0);
            if (t < 15) { asm volatile("s_waitcnt vmcnt(6)" ::: "memory"); }
            else        { asm volatile("s_waitcnt vmcnt(0)" ::: "memory"); }
            __builtin_amdgcn_s_barrier();
        }

        // ---------- phase 3: kk=1, nfrags {0,1} ----------
        {
            bf16x8 av[4], bv0, bv1;
#pragma unroll
            for (int mf = 0; mf < 4; ++mf) av[mf] = FRAG(Ab1, arow + mf * 16);
            bv0 = FRAG(Bb1, brow);
            bv1 = FRAG(Bb1, brow + 16);
            if (t < 14) STAGE_A(c, 0, t + 2);
            __builtin_amdgcn_s_barrier();
            asm volatile("s_waitcnt lgkmcnt(0)" ::: "memory");
            __builtin_amdgcn_sched_barrier(0);
            __builtin_amdgcn_s_setprio(1);
#pragma unroll
            for (int mf = 0; mf < 4; ++mf) {
                acc[mf][0] = MFMA16(av[mf], bv0, acc[mf][0]);
                acc[mf][1] = MFMA16(av[mf], bv1, acc[mf][1]);
            }
            __builtin_amdgcn_s_setprio(0);
            __builtin_amdgcn_s_barrier();

            // ---------- phase 4: kk=1, nfrags {2,3} ----------
            bv0 = FRAG(Bb1, brow + 32);
            bv1 = FRAG(Bb1, brow + 48);
            if (t < 14) STAGE_B(c, 0, t + 2);
            __builtin_amdgcn_s_barrier();
            asm volatile("s_waitcnt lgkmcnt(0)" ::: "memory");
            __builtin_amdgcn_sched_barrier(0);
            __builtin_amdgcn_s_setprio(1);
#pragma unroll
            for (int mf = 0; mf < 4; ++mf) {
                acc[mf][2] = MFMA16(av[mf], bv0, acc[mf][2]);
                acc[mf][3] = MFMA16(av[mf], bv1, acc[mf][3]);
            }
            __builtin_amdgcn_s_setprio(0);
            if (t < 14)      { asm volatile("s_waitcnt vmcnt(6)" ::: "memory"); }
            else if (t == 14){ asm volatile("s_waitcnt vmcnt(3)" ::: "memory"); }
            __builtin_amdgcn_s_barrier();
        }
    }

    // epilogue: coalesced scatter [b][h][s][hd] (proj uniform per block: 128|1024)
#pragma unroll
    for (int nf = 0; nf < 4; ++nf) {
        const int col = n0 + wn * 64 + nf * 16 + l15;
        const int proj = col >> 10, rem = col & 1023;
        const int h = rem >> 6, hd = rem & 63;
        const float* bp = proj == 0 ? bq : (proj == 1 ? bk : bv);
        const float bias = bp[rem];
        const float scl = (proj == 0) ? 0.125f : 1.0f;
        unsigned short* dst = proj == 0 ? Qo : (proj == 1 ? Ko : Vo);
#pragma unroll
        for (int mf = 0; mf < 4; ++mf) {
#pragma unroll
            for (int r = 0; r < 4; ++r) {
                const int m = m0 + wm * 64 + mf * 16 + g * 4 + r;
                const int bb = m >> 11, s = m & 2047;
                dst[(size_t)((bb * NH + h) * SEQ + s) * HDIM + hd] =
                    f2bf((acc[mf][nf][r] + bias) * scl);
            }
        }
    }
#undef STAGE_A
#undef STAGE_B
#undef FRAG
}

// ---------------- V transpose: [b][h][s][hd] -> [b][h][hd][s] ----------------
__global__ __launch_bounds__(256) void k_trv(const unsigned short* __restrict__ V,
                                             unsigned short* __restrict__ Vt) {
    __shared__ unsigned short tl[64][80];
    const int bh = blockIdx.y, s0 = blockIdx.x * 64;
    const int tid = threadIdx.x;
#pragma unroll
    for (int it = 0; it < 2; ++it) {
        const int c = it * 256 + tid;        // 0..511
        const int sl = c >> 3, hs = c & 7;
        i32x4 v = *(const i32x4*)(V + (size_t)(bh * SEQ + s0 + sl) * HDIM + hs * 8);
        union { i32x4 v; unsigned short u[8]; } uu;
        uu.v = v;
#pragma unroll
        for (int j = 0; j < 8; ++j) tl[hs * 8 + j][sl] = uu.u[j];
    }
    __syncthreads();
#pragma unroll
    for (int it = 0; it < 2; ++it) {
        const int c = it * 256 + tid;
        const int hd = c >> 3, ss = c & 7;
        i32x4 o = *(const i32x4*)(&tl[hd][ss * 8]);
        *(i32x4*)(Vt + (size_t)(bh * HDIM + hd) * SEQ + s0 + ss * 8) = o;
    }
}

// ---------------- sliding-window flash attention (single-pass softmax) ----------------
__global__ __launch_bounds__(256) void k_attn(const unsigned short* __restrict__ Qg,
                                              const unsigned short* __restrict__ Kg,
                                              const unsigned short* __restrict__ Vtg,
                                              const float* __restrict__ amask,
                                              float* __restrict__ out) {
    __shared__ unsigned short kl[224 * 64];
    __shared__ unsigned short vl[64 * 224];
    __shared__ unsigned short pl[4 * 16 * 160];
    const int bid0 = blockIdx.x;
    const int bid = (bid0 & 7) * 256 + (bid0 >> 3);  // XCD swizzle
    const int bh = bid >> 5, qb = bid & 31;
    const int b = bh >> 4, h = bh & 15;
    const int q0 = qb << 6;
    const int kstart = q0 - 144;
    const int tid = threadIdx.x, lane = tid & 63, w = tid >> 6;
    const int l15 = lane & 15, g = lane >> 4;

#pragma unroll
    for (int it = 0; it < 7; ++it) {
        const int c = it * 256 + tid;
        {
            const int row = c >> 3, sl = c & 7;
            const int key = kstart + row;
            i32x4 v = {0, 0, 0, 0};
            if ((unsigned)key < (unsigned)SEQ)
                v = *(const i32x4*)(Kg + (size_t)(bh * SEQ + key) * HDIM + sl * 8);
            *(i32x4*)((char*)kl + ((row * 128 + sl * 16) ^ ((row & 7) << 4))) = v;
        }
        {
            const int row = c / 28, sl = c - row * 28;
            const int key0 = kstart + sl * 8;
            i32x4 v = {0, 0, 0, 0};
            if ((unsigned)key0 < (unsigned)SEQ)
                v = *(const i32x4*)(Vtg + (size_t)(bh * HDIM + row) * SEQ + key0);
            *(i32x4*)((char*)vl + ((row * 448 + sl * 16) ^ ((row & 7) << 4))) = v;
        }
    }
    const int iq = q0 + w * 16 + l15;
    const bf16x8 qf0 = *(const bf16x8*)(Qg + (size_t)(bh * SEQ + iq) * HDIM + g * 8);
    const bf16x8 qf1 = *(const bf16x8*)(Qg + (size_t)(bh * SEQ + iq) * HDIM + 32 + g * 8);
    __syncthreads();

    char* pbase = (char*)pl + w * 5120;
    const int swq = (l15 & 7) << 4;
    float s[40];

    __builtin_amdgcn_s_setprio(1);
#pragma unroll
    for (int t = 0; t < 5; ++t) {
        const int tloc = w * 16 + t * 32;
        bf16x8 kf[2][2];
#pragma unroll
        for (int m = 0; m < 2; ++m) {
            const int row = tloc + m * 16 + l15;
            const int swz = (row & 7) << 4;
            kf[m][0] = *(const bf16x8*)((const char*)kl + ((row * 128 + g * 16) ^ swz));
            kf[m][1] = *(const bf16x8*)((const char*)kl + ((row * 128 + 64 + g * 16) ^ swz));
        }
        f32x4 sa0 = {0.f, 0.f, 0.f, 0.f}, sa1 = {0.f, 0.f, 0.f, 0.f};
        sa0 = MFMA16(kf[0][0], qf0, sa0);
        sa0 = MFMA16(kf[0][1], qf1, sa0);
        sa1 = MFMA16(kf[1][0], qf0, sa1);
        sa1 = MFMA16(kf[1][1], qf1, sa1);
#pragma unroll
        for (int f = 0; f < 2; ++f) {
            const int jb = kstart + tloc + f * 16 + g * 4;
            float4 m4 = {0.f, 0.f, 0.f, 0.f};
            if ((unsigned)jb < (unsigned)SEQ) m4 = *(const float4*)(amask + b * SEQ + jb);
            const float mvv[4] = {m4.x, m4.y, m4.z, m4.w};
#pragma unroll
            for (int r = 0; r < 4; ++r) {
                const int jg = jb + r;
                const float sc = (f == 0 ? sa0[r] : sa1[r]) + mvv[r];
                const bool ok = (jg >= 0) && (jg <= iq) && (iq - jg <= 128);
                s[t * 8 + f * 4 + r] = ok ? sc : -3.0e38f;
            }
        }
    }
    __builtin_amdgcn_s_setprio(0);

    float tr[20];
#pragma unroll
    for (int i = 0; i < 20; ++i) tr[i] = fmaxf(s[i], s[i + 20]);
#pragma unroll
    for (int i = 0; i < 10; ++i) tr[i] = fmaxf(tr[i], tr[i + 10]);
#pragma unroll
    for (int i = 0; i < 5; ++i) tr[i] = fmaxf(tr[i], tr[i + 5]);
    float m = fmaxf(fmaxf(tr[0], tr[1]), fmaxf(tr[2], fmaxf(tr[3], tr[4])));
    m = fmaxf(m, __shfl_xor(m, 16));
    m = fmaxf(m, __shfl_xor(m, 32));

    float ls0 = 0.f, ls1 = 0.f, ls2 = 0.f, ls3 = 0.f;
#pragma unroll
    for (int i = 0; i < 40; i += 4) {
        float p0 = exp2f((s[i + 0] - m) * 1.44269504f);
        float p1 = exp2f((s[i + 1] - m) * 1.44269504f);
        float p2 = exp2f((s[i + 2] - m) * 1.44269504f);
        float p3 = exp2f((s[i + 3] - m) * 1.44269504f);
        s[i + 0] = p0; s[i + 1] = p1; s[i + 2] = p2; s[i + 3] = p3;
        ls0 += p0; ls1 += p1; ls2 += p2; ls3 += p3;
    }
    float l = (ls0 + ls1) + (ls2 + ls3);
    l += __shfl_xor(l, 16);
    l += __shfl_xor(l, 32);

#pragma unroll
    for (int t = 0; t < 5; ++t) {
#pragma unroll
        for (int f = 0; f < 2; ++f) {
            u16x4 pu = {f2bf(s[t * 8 + f * 4 + 0]), f2bf(s[t * 8 + f * 4 + 1]),
                        f2bf(s[t * 8 + f * 4 + 2]), f2bf(s[t * 8 + f * 4 + 3])};
            *(u16x4*)(pbase + ((l15 * 320 + t * 64 + f * 32 + g * 8) ^ swq)) = pu;
        }
    }
    asm volatile("s_waitcnt lgkmcnt(0)" ::: "memory");
    __builtin_amdgcn_sched_barrier(0);

    f32x4 acc[4];
#pragma unroll
    for (int i = 0; i < 4; ++i) acc[i] = (f32x4){0.f, 0.f, 0.f, 0.f};
    __builtin_amdgcn_s_setprio(1);
#pragma unroll
    for (int t = 0; t < 5; ++t) {
        const int tloc = w * 16 + t * 32;
        const bf16x8 pf = *(const bf16x8*)(pbase + ((l15 * 320 + t * 64 + g * 16) ^ swq));
#pragma unroll
        for (int fn = 0; fn < 4; ++fn) {
            const int vrow = fn * 16 + l15;
            const bf16x8 vf = *(const bf16x8*)((const char*)vl +
                ((vrow * 448 + tloc * 2 + g * 16) ^ ((vrow & 7) << 4)));
            acc[fn] = MFMA16(pf, vf, acc[fn]);
        }
    }
    __builtin_amdgcn_s_setprio(0);

    float linv[4];
#pragma unroll
    for (int r = 0; r < 4; ++r) linv[r] = 1.0f / __shfl(l, g * 4 + r);
#pragma unroll
    for (int fn = 0; fn < 4; ++fn) {
#pragma unroll
        for (int r = 0; r < 4; ++r) {
            const int qrow = q0 + w * 16 + g * 4 + r;
            out[(size_t)(b * SEQ + qrow) * DMODEL + h * HDIM + fn * 16 + l15] =
                acc[fn][r] * linv[r];
        }
    }
}

extern "C" void kernel_launch(void* const* d_in, const int* in_sizes, int n_in,
                              void* d_out, int out_size, void* d_ws, size_t ws_size,
                              hipStream_t stream) {
    const float* hs = (const float*)d_in[0];
    const float* amask = (const float*)d_in[1];
    const float* wq = (const float*)d_in[2];
    const float* bq = (const float*)d_in[3];
    const float* wk = (const float*)d_in[4];
    const float* bk = (const float*)d_in[5];
    const float* wv = (const float*)d_in[6];
    const float* bv = (const float*)d_in[7];
    float* out = (float*)d_out;

    char* p = (char*)d_ws;
    unsigned short* Xbf = (unsigned short*)p;                          // 16 MB
    unsigned short* Wbf = (unsigned short*)(p + 16777216);             // 6 MB
    unsigned short* Qb = (unsigned short*)(p + 16777216 + 6291456);    // 16 MB
    unsigned short* Kb = Qb + 8388608;                                 // 16 MB
    unsigned short* Vb = Kb + 8388608;                                 // 16 MB
    unsigned short* Vtb = Xbf;  // alias: X fully consumed by GEMM before k_trv

    k_cvt<<<11264, 256, 0, stream>>>(hs, wq, wk, wv, Xbf, Wbf);
    k_qkv<<<768, 512, 0, stream>>>(Xbf, Wbf, bq, bk, bv, Qb, Kb, Vb);
    k_trv<<<dim3(32, 64), 256, 0, stream>>>(Vb, Vtb);
    k_attn<<<2048, 256, 0, stream>>>(Qb, Kb, Vtb, amask, out);
}

// Round 14
// 129.947 us; speedup vs baseline: 1.1359x; 1.1359x over previous
//
#include <hip/hip_runtime.h>
#include <cstdint>

#define BDIM 4
#define SEQ 2048
#define DMODEL 1024
#define NH 16
#define HDIM 64

typedef __attribute__((ext_vector_type(8))) short bf16x8;
typedef __attribute__((ext_vector_type(4))) float f32x4;
typedef __attribute__((ext_vector_type(4))) int i32x4;
typedef __attribute__((ext_vector_type(4))) unsigned short u16x4;

#define MFMA16(a, b, c) __builtin_amdgcn_mfma_f32_16x16x32_bf16(a, b, c, 0, 0, 0)

__device__ __forceinline__ unsigned short f2bf(float x) {
    unsigned int u = __float_as_uint(x);
    unsigned int r = (u + 0x7FFFu + ((u >> 16) & 1u)) >> 16;
    return (unsigned short)r;
}

__device__ __forceinline__ void gload16(const void* g, void* l) {
    __builtin_amdgcn_global_load_lds(
        (const __attribute__((address_space(1))) unsigned int*)g,
        (__attribute__((address_space(3))) unsigned int*)l, 16, 0, 0);
}

// ---------------- fused convert fp32 -> bf16 (X and Wq/Wk/Wv in one launch) ----------------
__global__ __launch_bounds__(256) void k_cvt(const float* __restrict__ hs,
                                             const float* __restrict__ wq,
                                             const float* __restrict__ wk,
                                             const float* __restrict__ wv,
                                             unsigned short* __restrict__ Xbf,
                                             unsigned short* __restrict__ Wbf) {
    int i = blockIdx.x * 256 + threadIdx.x;  // float4 index; 11264 blocks total
    if (i < 2097152) {                       // X: 8192 blocks exactly (block-uniform)
        float4 v = ((const float4*)hs)[i];
        u16x4 o = {f2bf(v.x), f2bf(v.y), f2bf(v.z), f2bf(v.w)};
        ((u16x4*)Xbf)[i] = o;
    } else {                                 // W: 3072 blocks
        int j = i - 2097152;                 // 0..786431
        int e = j << 2;
        int which = e >> 20;
        int off = e & 0xFFFFF;
        const float* s = which == 0 ? wq : (which == 1 ? wk : wv);
        float4 v = *(const float4*)(s + off);
        u16x4 o = {f2bf(v.x), f2bf(v.y), f2bf(v.z), f2bf(v.w)};
        ((u16x4*)Wbf)[j] = o;
    }
}

// ---------------- fused QKV GEMM: C = X (8192x1024) * W^T (3072x1024) ----------------
// Measured-optimal structure (73.5us / ~700TF): 2-barrier compiler-scheduled
// loop, NO in-loop asm fences (m141-class regressions), coalesced epilogue
// (all outputs [b][h][s][hd], hd contiguous across lanes; V-transposed stores
// scatter 4KB-strided -> +13..21us, measured r3/r8/r11).
// 13-round ledger: every deviation (BK64, ring-4, 8-phase at 3 geometries,
// fused V-transpose) lost 9-33us. K=1024 (16-32 iters) cannot amortize
// deep-pipeline prologues; 6-waves/SIMD TLP + compiler scheduling wins here.
__global__ __launch_bounds__(256) void k_qkv(const unsigned short* __restrict__ X,
                                             const unsigned short* __restrict__ W,
                                             const float* __restrict__ bq,
                                             const float* __restrict__ bk,
                                             const float* __restrict__ bv,
                                             unsigned short* __restrict__ Qo,
                                             unsigned short* __restrict__ Ko,
                                             unsigned short* __restrict__ Vo) {
    __shared__ unsigned short ldsA[128 * 32];
    __shared__ unsigned short ldsB[128 * 32];
    const int tid = threadIdx.x;
    const int lane = tid & 63, wid = tid >> 6;
    const int wm = wid >> 1, wn = wid & 1;
    const int l15 = lane & 15, g = lane >> 4;
    const int m0 = blockIdx.y * 128, n0 = blockIdx.x * 128;

    f32x4 acc[4][4];
#pragma unroll
    for (int i = 0; i < 4; ++i)
#pragma unroll
        for (int j = 0; j < 4; ++j) acc[i][j] = (f32x4){0.f, 0.f, 0.f, 0.f};

    for (int kt = 0; kt < 32; ++kt) {
        const int k0 = kt << 5;
        __syncthreads();
#pragma unroll
        for (int it = 0; it < 2; ++it) {
            const int c = it * 256 + tid;
            const int row = c >> 2, sl = c & 3;
            gload16(X + (size_t)(m0 + row) * DMODEL + k0 + sl * 8, (char*)ldsA + c * 16);
            gload16(W + (size_t)(n0 + row) * DMODEL + k0 + sl * 8, (char*)ldsB + c * 16);
        }
        __syncthreads();
        bf16x8 a[4], b[4];
#pragma unroll
        for (int f = 0; f < 4; ++f) {
            a[f] = *(const bf16x8*)((const char*)ldsA + (wm * 64 + f * 16 + l15) * 64 + g * 16);
            b[f] = *(const bf16x8*)((const char*)ldsB + (wn * 64 + f * 16 + l15) * 64 + g * 16);
        }
#pragma unroll
        for (int fm = 0; fm < 4; ++fm)
#pragma unroll
            for (int fn = 0; fn < 4; ++fn) acc[fm][fn] = MFMA16(a[fm], b[fn], acc[fm][fn]);
    }

// epilogue: scatter into Q/K/V [b][h][s][hd] bf16, bias add, Q pre-scaled by 0.125
#pragma unroll
    for (int fn = 0; fn < 4; ++fn) {
        const int col = n0 + wn * 64 + fn * 16 + l15;
        const int proj = col >> 10, rem = col & 1023;
        const int h = rem >> 6, hd = rem & 63;
        const float* bp = proj == 0 ? bq : (proj == 1 ? bk : bv);
        const float bias = bp[rem];
        const float scl = (proj == 0) ? 0.125f : 1.0f;
        unsigned short* dst = proj == 0 ? Qo : (proj == 1 ? Ko : Vo);
#pragma unroll
        for (int fm = 0; fm < 4; ++fm) {
#pragma unroll
            for (int r = 0; r < 4; ++r) {
                const int m = m0 + wm * 64 + fm * 16 + g * 4 + r;
                const int bb = m >> 11, s = m & 2047;
                dst[(size_t)((bb * NH + h) * SEQ + s) * HDIM + hd] =
                    f2bf((acc[fm][fn][r] + bias) * scl);
            }
        }
    }
}

// ---------------- V transpose: [b][h][s][hd] -> [b][h][hd][s] ----------------
// 64x64 tile; 512 threads x 8 elems each side; row stride 80 u16 (16B-aligned).
// Measured ~7us. Fusing this into qkv (r11) or attn (r8) measured worse.
__global__ __launch_bounds__(256) void k_trv(const unsigned short* __restrict__ V,
                                             unsigned short* __restrict__ Vt) {
    __shared__ unsigned short tl[64][80];
    const int bh = blockIdx.y, s0 = blockIdx.x * 64;
    const int tid = threadIdx.x;
#pragma unroll
    for (int it = 0; it < 2; ++it) {
        const int c = it * 256 + tid;        // 0..511
        const int sl = c >> 3, hs = c & 7;   // sl: s-row 0..63, hs: 8-elem hd slot
        i32x4 v = *(const i32x4*)(V + (size_t)(bh * SEQ + s0 + sl) * HDIM + hs * 8);
        union { i32x4 v; unsigned short u[8]; } uu;
        uu.v = v;
#pragma unroll
        for (int j = 0; j < 8; ++j) tl[hs * 8 + j][sl] = uu.u[j];
    }
    __syncthreads();
#pragma unroll
    for (int it = 0; it < 2; ++it) {
        const int c = it * 256 + tid;
        const int hd = c >> 3, ss = c & 7;   // hd 0..63, ss: 8-elem s slot
        i32x4 o = *(const i32x4*)(&tl[hd][ss * 8]);
        *(i32x4*)(Vt + (size_t)(bh * HDIM + hd) * SEQ + s0 + ss * 8) = o;
    }
}

// ---------------- sliding-window flash attention (single-pass softmax) ----------------
// block = (b,h, 64 queries); 4 waves x 16 queries; keys staged [q0-144, q0+79].
// Window (129 keys) fits staged range: all QK^T -> registers, ONE max/exp/sum
// pass, un-rescaled PV, final 1/l. ~32us (~60% of HBM staging floor).
__global__ __launch_bounds__(256) void k_attn(const unsigned short* __restrict__ Qg,
                                              const unsigned short* __restrict__ Kg,
                                              const unsigned short* __restrict__ Vtg,
                                              const float* __restrict__ amask,
                                              float* __restrict__ out) {
    __shared__ unsigned short kl[224 * 64];      // swizzled rows (stride 128B)
    __shared__ unsigned short vl[64 * 224];      // swizzled rows (stride 448B)
    __shared__ unsigned short pl[4 * 16 * 160];  // per-wave 16x160 P tile
    const int bid0 = blockIdx.x;
    const int bid = (bid0 & 7) * 256 + (bid0 >> 3);  // XCD swizzle (2048 % 8 == 0)
    const int bh = bid >> 5, qb = bid & 31;
    const int b = bh >> 4, h = bh & 15;
    const int q0 = qb << 6;
    const int kstart = q0 - 144;
    const int tid = threadIdx.x, lane = tid & 63, w = tid >> 6;
    const int l15 = lane & 15, g = lane >> 4;

#pragma unroll
    for (int it = 0; it < 7; ++it) {
        const int c = it * 256 + tid;
        {  // K tile: row = key, 64 bf16 per row
            const int row = c >> 3, sl = c & 7;
            const int key = kstart + row;
            i32x4 v = {0, 0, 0, 0};
            if ((unsigned)key < (unsigned)SEQ)
                v = *(const i32x4*)(Kg + (size_t)(bh * SEQ + key) * HDIM + sl * 8);
            *(i32x4*)((char*)kl + ((row * 128 + sl * 16) ^ ((row & 7) << 4))) = v;
        }
        {  // Vt tile: row = hd, 224 keys per row
            const int row = c / 28, sl = c - row * 28;
            const int key0 = kstart + sl * 8;
            i32x4 v = {0, 0, 0, 0};
            if ((unsigned)key0 < (unsigned)SEQ)
                v = *(const i32x4*)(Vtg + (size_t)(bh * HDIM + row) * SEQ + key0);
            *(i32x4*)((char*)vl + ((row * 448 + sl * 16) ^ ((row & 7) << 4))) = v;
        }
    }
    const int iq = q0 + w * 16 + l15;
    const bf16x8 qf0 = *(const bf16x8*)(Qg + (size_t)(bh * SEQ + iq) * HDIM + g * 8);
    const bf16x8 qf1 = *(const bf16x8*)(Qg + (size_t)(bh * SEQ + iq) * HDIM + 32 + g * 8);
    __syncthreads();

    char* pbase = (char*)pl + w * 5120;
    const int swq = (l15 & 7) << 4;
    float s[40];

    // ---- phase 1: all QK^T chunks, masked scores into registers ----
    __builtin_amdgcn_s_setprio(1);
#pragma unroll
    for (int t = 0; t < 5; ++t) {
        const int tloc = w * 16 + t * 32;
        bf16x8 kf[2][2];
#pragma unroll
        for (int m = 0; m < 2; ++m) {
            const int row = tloc + m * 16 + l15;
            const int swz = (row & 7) << 4;
            kf[m][0] = *(const bf16x8*)((const char*)kl + ((row * 128 + g * 16) ^ swz));
            kf[m][1] = *(const bf16x8*)((const char*)kl + ((row * 128 + 64 + g * 16) ^ swz));
        }
        f32x4 sa0 = {0.f, 0.f, 0.f, 0.f}, sa1 = {0.f, 0.f, 0.f, 0.f};
        sa0 = MFMA16(kf[0][0], qf0, sa0);
        sa0 = MFMA16(kf[0][1], qf1, sa0);
        sa1 = MFMA16(kf[1][0], qf0, sa1);
        sa1 = MFMA16(kf[1][1], qf1, sa1);
#pragma unroll
        for (int f = 0; f < 2; ++f) {
            const int jb = kstart + tloc + f * 16 + g * 4;
            float4 m4 = {0.f, 0.f, 0.f, 0.f};
            if ((unsigned)jb < (unsigned)SEQ) m4 = *(const float4*)(amask + b * SEQ + jb);
            const float mvv[4] = {m4.x, m4.y, m4.z, m4.w};
#pragma unroll
            for (int r = 0; r < 4; ++r) {
                const int jg = jb + r;
                const float sc = (f == 0 ? sa0[r] : sa1[r]) + mvv[r];
                const bool ok = (jg >= 0) && (jg <= iq) && (iq - jg <= 128);
                s[t * 8 + f * 4 + r] = ok ? sc : -3.0e38f;
            }
        }
    }
    __builtin_amdgcn_s_setprio(0);

    // ---- phase 2: single softmax pass ----
    float tr[20];
#pragma unroll
    for (int i = 0; i < 20; ++i) tr[i] = fmaxf(s[i], s[i + 20]);
#pragma unroll
    for (int i = 0; i < 10; ++i) tr[i] = fmaxf(tr[i], tr[i + 10]);
#pragma unroll
    for (int i = 0; i < 5; ++i) tr[i] = fmaxf(tr[i], tr[i + 5]);
    float m = fmaxf(fmaxf(tr[0], tr[1]), fmaxf(tr[2], fmaxf(tr[3], tr[4])));
    m = fmaxf(m, __shfl_xor(m, 16));
    m = fmaxf(m, __shfl_xor(m, 32));  // always finite: key j==iq is in range

    float ls0 = 0.f, ls1 = 0.f, ls2 = 0.f, ls3 = 0.f;
#pragma unroll
    for (int i = 0; i < 40; i += 4) {
        float p0 = exp2f((s[i + 0] - m) * 1.44269504f);
        float p1 = exp2f((s[i + 1] - m) * 1.44269504f);
        float p2 = exp2f((s[i + 2] - m) * 1.44269504f);
        float p3 = exp2f((s[i + 3] - m) * 1.44269504f);
        s[i + 0] = p0; s[i + 1] = p1; s[i + 2] = p2; s[i + 3] = p3;
        ls0 += p0; ls1 += p1; ls2 += p2; ls3 += p3;
    }
    float l = (ls0 + ls1) + (ls2 + ls3);
    l += __shfl_xor(l, 16);
    l += __shfl_xor(l, 32);

    // ---- phase 3: write P (bf16) to per-wave LDS tile ----
#pragma unroll
    for (int t = 0; t < 5; ++t) {
#pragma unroll
        for (int f = 0; f < 2; ++f) {
            u16x4 pu = {f2bf(s[t * 8 + f * 4 + 0]), f2bf(s[t * 8 + f * 4 + 1]),
                        f2bf(s[t * 8 + f * 4 + 2]), f2bf(s[t * 8 + f * 4 + 3])};
            *(u16x4*)(pbase + ((l15 * 320 + t * 64 + f * 32 + g * 8) ^ swq)) = pu;
        }
    }
    asm volatile("s_waitcnt lgkmcnt(0)" ::: "memory");
    __builtin_amdgcn_sched_barrier(0);

    // ---- phase 4: PV, no rescaling ----
    f32x4 acc[4];
#pragma unroll
    for (int i = 0; i < 4; ++i) acc[i] = (f32x4){0.f, 0.f, 0.f, 0.f};
    __builtin_amdgcn_s_setprio(1);
#pragma unroll
    for (int t = 0; t < 5; ++t) {
        const int tloc = w * 16 + t * 32;
        const bf16x8 pf = *(const bf16x8*)(pbase + ((l15 * 320 + t * 64 + g * 16) ^ swq));
#pragma unroll
        for (int fn = 0; fn < 4; ++fn) {
            const int vrow = fn * 16 + l15;
            const bf16x8 vf = *(const bf16x8*)((const char*)vl +
                ((vrow * 448 + tloc * 2 + g * 16) ^ ((vrow & 7) << 4)));
            acc[fn] = MFMA16(pf, vf, acc[fn]);
        }
    }
    __builtin_amdgcn_s_setprio(0);

    float linv[4];
#pragma unroll
    for (int r = 0; r < 4; ++r) linv[r] = 1.0f / __shfl(l, g * 4 + r);
#pragma unroll
    for (int fn = 0; fn < 4; ++fn) {
#pragma unroll
        for (int r = 0; r < 4; ++r) {
            const int qrow = q0 + w * 16 + g * 4 + r;
            out[(size_t)(b * SEQ + qrow) * DMODEL + h * HDIM + fn * 16 + l15] =
                acc[fn][r] * linv[r];
        }
    }
}

extern "C" void kernel_launch(void* const* d_in, const int* in_sizes, int n_in,
                              void* d_out, int out_size, void* d_ws, size_t ws_size,
                              hipStream_t stream) {
    const float* hs = (const float*)d_in[0];
    const float* amask = (const float*)d_in[1];
    const float* wq = (const float*)d_in[2];
    const float* bq = (const float*)d_in[3];
    const float* wk = (const float*)d_in[4];
    const float* bk = (const float*)d_in[5];
    const float* wv = (const float*)d_in[6];
    const float* bv = (const float*)d_in[7];
    float* out = (float*)d_out;

    char* p = (char*)d_ws;
    unsigned short* Xbf = (unsigned short*)p;                          // 16 MB
    unsigned short* Wbf = (unsigned short*)(p + 16777216);             // 6 MB
    unsigned short* Qb = (unsigned short*)(p + 16777216 + 6291456);    // 16 MB
    unsigned short* Kb = Qb + 8388608;                                 // 16 MB
    unsigned short* Vb = Kb + 8388608;                                 // 16 MB
    unsigned short* Vtb = Xbf;  // alias: X fully consumed by GEMM before k_trv

    k_cvt<<<11264, 256, 0, stream>>>(hs, wq, wk, wv, Xbf, Wbf);
    k_qkv<<<dim3(24, 64), 256, 0, stream>>>(Xbf, Wbf, bq, bk, bv, Qb, Kb, Vb);
    k_trv<<<dim3(32, 64), 256, 0, stream>>>(Vb, Vtb);
    k_attn<<<2048, 256, 0, stream>>>(Qb, Kb, Vtb, amask, out);
}